// Round 1
// 895.146 us; speedup vs baseline: 1.0109x; 1.0109x over previous
//
#include <hip/hip_runtime.h>
#include <hip/hip_bf16.h>

// Problem: B=32, R=5, N=1024, D=256, H=256
// out[b,n,h] = sum_d nodes[b,n,d]*w0[h,d]
//            + sum_r (1/c[b,r,n]) * sum_d nodes[b,n,d]*wr[r,h,d]
// c[b,r,n] = sum_j adj[b,r,n,j]  (1 if 0)

#define BB 32
#define RR 5
#define NN 1024
#define DD 256
#define HH 256
#define MM (BB * NN)   // 32768 global rows

// prep_kernel block partition
#define RS_BLOCKS 40960                 // rowsum: 4 rows (waves) per block
#define CVN_BLOCKS 8192                 // nodes cvt: 1024 elems per block
#define CVW_BLOCKS 384                  // weights cvt: w0 (64 blocks) + wr (320 blocks)

typedef __attribute__((ext_vector_type(8))) short short8;
typedef __attribute__((ext_vector_type(4))) float f32x4;

#define GAS(p) ((const __attribute__((address_space(1))) void*)(p))
#define LAS(p) ((__attribute__((address_space(3))) void*)(p))

__device__ __forceinline__ unsigned short f2bf(float f) {
    unsigned int u = __float_as_uint(f);
    unsigned int r = (u + 0x7FFFu + ((u >> 16) & 1u)) >> 16;
    return (unsigned short)r;
}

// Fused preprocessing: adj row-sums + fp32->bf16 casts, partitioned by blockIdx.
//  [0, RS_BLOCKS)                  : rowsum of adj -> inv_c  (1 wave per 1024-float row)
//  [RS_BLOCKS, +CVN_BLOCKS)        : cvt nodes -> nodesb
//  [RS_BLOCKS+CVN_BLOCKS, +CVW)    : cvt w0|wr -> wb (w0 occupies exactly 64 blocks, no straddle)
__global__ __launch_bounds__(256) void prep_kernel(
    const float* __restrict__ nodes, const float* __restrict__ adj,
    const float* __restrict__ w0,    const float* __restrict__ wr,
    unsigned short* __restrict__ nodesb, unsigned short* __restrict__ wb,
    float* __restrict__ inv_c) {
    const int bid = blockIdx.x;
    const int tid = threadIdx.x;
    if (bid < RS_BLOCKS) {
        const int wave = bid * 4 + (tid >> 6);
        const int lane = tid & 63;
        const float4* row4 = reinterpret_cast<const float4*>(adj + (size_t)wave * NN);
        float s = 0.f;
#pragma unroll
        for (int i = 0; i < 4; ++i) {
            float4 v = row4[lane + 64 * i];
            s += (v.x + v.y) + (v.z + v.w);
        }
#pragma unroll
        for (int off = 32; off > 0; off >>= 1) s += __shfl_down(s, off, 64);
        if (lane == 0) {
            float c = (s == 0.f) ? 1.f : s;
            inv_c[wave] = 1.f / c;
        }
    } else if (bid < RS_BLOCKS + CVN_BLOCKS) {
        const int i = ((bid - RS_BLOCKS) * 256 + tid) * 4;
        float4 v = *reinterpret_cast<const float4*>(nodes + i);
        ushort4 o;
        o.x = f2bf(v.x); o.y = f2bf(v.y); o.z = f2bf(v.z); o.w = f2bf(v.w);
        *reinterpret_cast<ushort4*>(nodesb + i) = o;
    } else {
        const int i = ((bid - RS_BLOCKS - CVN_BLOCKS) * 256 + tid) * 4;
        const float* src = (i < HH * DD) ? (w0 + i) : (wr + (i - HH * DD));
        float4 v = *reinterpret_cast<const float4*>(src);
        ushort4 o;
        o.x = f2bf(v.x); o.y = f2bf(v.y); o.z = f2bf(v.z); o.w = f2bf(v.w);
        *reinterpret_cast<ushort4*>(wb + i) = o;
    }
}

// Fused 6-set GEMM + per-row combine.  2-phase double-buffered K-loop (T3 minimum):
//   issue global_load_lds for tile k+1 into buf^1, ds_read+MFMA from buf,
//   one __syncthreads (= vmcnt(0)+lgkmcnt(0)+barrier) per K-step.
// Block = 256 thr (4 waves). Block tile: 64 rows x 64 cols x 6 sets, BK=32.
// LDS: 2 x (A 64x32 bf16 + B 6x64x32 bf16) = 56 KB, staged via global_load_lds w=16.
// Wave wv computes cols [wv*16, wv*16+16) for all 6 sets (acc = 6*4 f32x4/lane).
__global__ __launch_bounds__(256) void gemm_kernel(
    const unsigned short* __restrict__ nodesb,
    const unsigned short* __restrict__ wb,
    const float* __restrict__ inv_c,
    float* __restrict__ out) {
    __shared__ unsigned short smem[2 * 14336];  // 2 x 28 KB: per buf [0,2048) A, [2048,14336) B
    __shared__ float s_inv[RR * 64];

    const int tid  = threadIdx.x;
    const int lane = tid & 63;
    const int wv   = tid >> 6;
    const int row_base = blockIdx.x * 64;
    const int col_base = blockIdx.y * 64;
    const int m    = lane & 15;
    const int quad = lane >> 4;

    // --- staging chunk setup: 28 x 1KB chunks per buf, wave wv owns chunks wv*7..wv*7+6
    const unsigned short* gp[7];
    int lo[7];
#pragma unroll
    for (int j = 0; j < 7; ++j) {
        const int c = wv * 7 + j;
        lo[j] = c * 512;                        // ushort index; c*1024 bytes
        if (c < 4) {
            const int u   = c * 64 + lane;      // 16B-unit index in A region
            const int row = u >> 2;
            const int kc  = u & 3;
            gp[j] = nodesb + (size_t)(row_base + row) * DD + kc * 8;
        } else {
            const int u    = (c - 4) * 64 + lane;
            const int col6 = u >> 2;            // 0..383 : set*64 + col
            const int kc   = u & 3;
            const int set  = col6 >> 6;
            const int col  = col6 & 63;
            gp[j] = wb + (size_t)(set * HH + col_base + col) * DD + kc * 8;
        }
    }

    f32x4 acc[6][4];
#pragma unroll
    for (int s = 0; s < 6; ++s)
#pragma unroll
        for (int t = 0; t < 4; ++t) acc[s][t] = (f32x4){0.f, 0.f, 0.f, 0.f};

    const int aoff = m * 32 + quad * 8;                   // +t*512
    const int boff = 2048 + (wv * 16 + m) * 32 + quad * 8;  // +s*1024

    // prologue: stage kt=0 into buf 0
#pragma unroll
    for (int j = 0; j < 7; ++j)
        __builtin_amdgcn_global_load_lds(GAS(gp[j]), LAS(smem + lo[j]), 16, 0, 0);
    __syncthreads();

    int cur = 0;
#pragma unroll
    for (int kt = 0; kt < 8; ++kt) {
        // issue next tile's staging into the other buffer (overlaps with compute below)
        if (kt < 7) {
            unsigned short* nb = smem + (cur ^ 1) * 14336;
#pragma unroll
            for (int j = 0; j < 7; ++j)
                __builtin_amdgcn_global_load_lds(GAS(gp[j] + (kt + 1) * 32), LAS(nb + lo[j]), 16, 0, 0);
        }
        // compute current buffer
        const unsigned short* aL = smem + cur * 14336 + aoff;
        const unsigned short* bL = smem + cur * 14336 + boff;
        short8 afr[4];
#pragma unroll
        for (int t = 0; t < 4; ++t)
            afr[t] = *reinterpret_cast<const short8*>(aL + t * 512);
#pragma unroll
        for (int s = 0; s < 6; ++s) {
            short8 bfr = *reinterpret_cast<const short8*>(bL + s * 2048);
#pragma unroll
            for (int t = 0; t < 4; ++t)
                acc[s][t] = __builtin_amdgcn_mfma_f32_16x16x32_bf16(afr[t], bfr, acc[s][t], 0, 0, 0);
        }
        __syncthreads();   // drains vmcnt(0) (next tile landed) + lgkmcnt; buffer flip safe
        cur ^= 1;
    }

    // --- epilogue: stage inv_c tile (5 x 64 floats) in LDS
    const int b  = row_base >> 10;
    const int n0 = row_base & (NN - 1);
#pragma unroll
    for (int i = tid; i < RR * 64; i += 256) {
        const int r = i >> 6, nl = i & 63;
        s_inv[i] = inv_c[((size_t)b * RR + r) * NN + n0 + nl];
    }
    __syncthreads();

    const int hcol = col_base + wv * 16 + m;
#pragma unroll
    for (int t = 0; t < 4; ++t) {
#pragma unroll
        for (int i = 0; i < 4; ++i) {
            const int rloc = t * 16 + quad * 4 + i;
            float v = acc[0][t][i];
#pragma unroll
            for (int r = 0; r < RR; ++r)
                v += s_inv[r * 64 + rloc] * acc[r + 1][t][i];
            out[(size_t)(row_base + rloc) * HH + hcol] = v;
        }
    }
}

extern "C" void kernel_launch(void* const* d_in, const int* in_sizes, int n_in,
                              void* d_out, int out_size, void* d_ws, size_t ws_size,
                              hipStream_t stream) {
    const float* nodes = (const float*)d_in[0];  // (B,N,D)
    const float* adj   = (const float*)d_in[1];  // (B,R,N,N)
    const float* w0    = (const float*)d_in[2];  // (H,D)
    const float* wr    = (const float*)d_in[3];  // (R,H,D)
    float* out = (float*)d_out;                  // (B,N,H)

    // Workspace layout
    unsigned short* nodesb = (unsigned short*)d_ws;                                  // M*D bf16
    unsigned short* wb     = (unsigned short*)((char*)d_ws + (size_t)MM * DD * 2);   // 6*H*D bf16
    float*          inv_c  = (float*)((char*)d_ws + (size_t)MM * DD * 2 + (size_t)6 * HH * DD * 2);

    prep_kernel<<<RS_BLOCKS + CVN_BLOCKS + CVW_BLOCKS, 256, 0, stream>>>(
        nodes, adj, w0, wr, nodesb, wb, inv_c);

    gemm_kernel<<<dim3(MM / 64, HH / 64), 256, 0, stream>>>(nodesb, wb, inv_c, out);
}